// Round 6
// baseline (364.188 us; speedup 1.0000x reference)
//
#include <hip/hip_runtime.h>

#define N_VOX 100000
#define KVOL 27
#define MPAIR 50000
#define CIN 64
#define COUT 64
#define TILES_PER_WAVE 8
#define NTILES 3125          // 50000 / 16, exact

typedef __attribute__((ext_vector_type(8))) short bf16x8;   // 8 bf16 = 4 VGPRs
typedef __attribute__((ext_vector_type(4))) float f32x4;

__device__ inline short f2bf(float f) {          // RNE f32 -> bf16
    union { float f; unsigned u; } v; v.f = f;
    return (short)((v.u + 0x7FFFu + ((v.u >> 16) & 1u)) >> 16);
}

// out[n][c] = bias[c]  (folds bias; clears the 0xAA poison)
__global__ void spconv_init_bias(const float* __restrict__ bias,
                                 float* __restrict__ out, int total) {
    int i = blockIdx.x * blockDim.x + threadIdx.x;
    if (i < total) out[i] = bias[i & (COUT - 1)];
}

// One wave per 16-pair tile: gather 16 x-rows -> bf16 A-frags,
// W[k] held as bf16 B-frags in VGPRs (amortized over TILES_PER_WAVE tiles),
// 8x mfma_f32_16x16x32_bf16, fp32 atomic scatter.
__global__ __launch_bounds__(256) void spconv_mfma(
    const float* __restrict__ x,
    const float* __restrict__ kern,
    const int*   __restrict__ in_map,
    const int*   __restrict__ out_map,
    float*       __restrict__ out)
{
    const int lane = threadIdx.x & 63;
    const int wave = threadIdx.x >> 6;
    const int k    = blockIdx.y;
    const int g    = lane >> 4;          // 16-lane group 0..3
    const int r16  = lane & 15;

    // ---- B fragments: frag[s][t] elem j = W[k][s*32 + g*8 + j][t*16 + r16]
    bf16x8 bfrag[2][4];
    {
        const float* wp = kern + (size_t)k * CIN * COUT;
        #pragma unroll
        for (int s = 0; s < 2; ++s)
            #pragma unroll
            for (int t = 0; t < 4; ++t) {
                const float* p = wp + (s * 32 + g * 8) * COUT + t * 16 + r16;
                bf16x8 f;
                #pragma unroll
                for (int j = 0; j < 8; ++j) f[j] = f2bf(p[j * COUT]);
                bfrag[s][t] = f;
            }
    }

    for (int it = 0; it < TILES_PER_WAVE; ++it) {
        int tile = (blockIdx.x * 4 + wave) * TILES_PER_WAVE + it;
        if (tile >= NTILES) break;               // wave-uniform
        int base = k * MPAIR + tile * 16;

        // A row index for this lane's group-row (4 lanes share each)
        int im = in_map[base + r16];

        // A fragments: frag[s] elem j = x[im][s*32 + g*8 + j]  (bf16)
        bf16x8 afrag[2];
        const float* xp = x + (size_t)im * CIN + g * 8;
        #pragma unroll
        for (int s = 0; s < 2; ++s) {
            f32x4 v0 = *(const f32x4*)(xp + s * 32);
            f32x4 v1 = *(const f32x4*)(xp + s * 32 + 4);
            bf16x8 f;
            f[0] = f2bf(v0[0]); f[1] = f2bf(v0[1]);
            f[2] = f2bf(v0[2]); f[3] = f2bf(v0[3]);
            f[4] = f2bf(v1[0]); f[5] = f2bf(v1[1]);
            f[6] = f2bf(v1[2]); f[7] = f2bf(v1[3]);
            afrag[s] = f;
        }

        // ---- 8 MFMAs: acc[t] over k-steps s=0,1
        f32x4 acc[4] = {{0.f,0.f,0.f,0.f},{0.f,0.f,0.f,0.f},
                        {0.f,0.f,0.f,0.f},{0.f,0.f,0.f,0.f}};
        #pragma unroll
        for (int t = 0; t < 4; ++t) {
            acc[t] = __builtin_amdgcn_mfma_f32_16x16x32_bf16(afrag[0], bfrag[0][t], acc[t], 0, 0, 0);
            acc[t] = __builtin_amdgcn_mfma_f32_16x16x32_bf16(afrag[1], bfrag[1][t], acc[t], 0, 0, 0);
        }

        // ---- scatter: lane covers out rows pair (g*4+r), col t*16+r16
        int orow[4];
        #pragma unroll
        for (int r = 0; r < 4; ++r) orow[r] = out_map[base + g * 4 + r];
        #pragma unroll
        for (int r = 0; r < 4; ++r) {
            float* op = out + (size_t)orow[r] * COUT + r16;
            #pragma unroll
            for (int t = 0; t < 4; ++t)
                atomicAdd(op + t * 16, acc[t][r]);
        }
    }
}

extern "C" void kernel_launch(void* const* d_in, const int* in_sizes, int n_in,
                              void* d_out, int out_size, void* d_ws, size_t ws_size,
                              hipStream_t stream) {
    const float* x       = (const float*)d_in[0];   // [N, CIN]
    const float* kern    = (const float*)d_in[1];   // [K, CIN, COUT]
    const float* bias    = (const float*)d_in[2];   // [1, COUT]
    const int*   in_map  = (const int*)d_in[3];     // [K, M] int32
    const int*   out_map = (const int*)d_in[4];     // [K, M] int32
    float*       out     = (float*)d_out;           // [N, COUT]

    int total = N_VOX * COUT;
    spconv_init_bias<<<(total + 255) / 256, 256, 0, stream>>>(bias, out, total);

    dim3 grid((NTILES + 4 * TILES_PER_WAVE - 1) / (4 * TILES_PER_WAVE), KVOL);  // 98 x 27
    spconv_mfma<<<grid, 256, 0, stream>>>(x, kern, in_map, out_map, out);
}